// Round 3
// baseline (501.353 us; speedup 1.0000x reference)
//
#include <hip/hip_runtime.h>

typedef unsigned short u16;
typedef __attribute__((ext_vector_type(8))) short bf16x8;
typedef __attribute__((ext_vector_type(8))) unsigned short u16x8;
typedef __attribute__((ext_vector_type(4))) float f32x4;
typedef __attribute__((ext_vector_type(4))) unsigned short u16x4;

#define Bn 8
#define Tn 4096
#define Cn 1024
#define HSn 128

__device__ __forceinline__ float bf2f(u16 b) {
    unsigned u = ((unsigned)b) << 16;
    return __builtin_bit_cast(float, u);
}
__device__ __forceinline__ u16 f2bf(float f) {
    unsigned u = __builtin_bit_cast(unsigned, f);
    unsigned r = (u + 0x7fffu + ((u >> 16) & 1u)) >> 16;
    return (u16)r;
}

// ---------------------------------------------------------------------------
// Kernel 1: W fp32 [k][n] (1024x128) -> Wt bf16 [n][k] (128x1024), x3.
// Softmax scale * log2(e) folded into Wq.
// ---------------------------------------------------------------------------
extern "C" __global__ __launch_bounds__(256) void head_wtrans(
    const float* __restrict__ Wq, const float* __restrict__ Wk,
    const float* __restrict__ Wv, u16* __restrict__ wt) {
    const float* W = (blockIdx.y == 0) ? Wq : (blockIdx.y == 1) ? Wk : Wv;
    const float scale =
        (blockIdx.y == 0) ? (0.08838834764831845f * 1.4426950408889634f) : 1.0f;
    u16* o = wt + (size_t)blockIdx.y * Cn * HSn;
    int tid = blockIdx.x * 256 + threadIdx.x;  // [0, 131072)
    int n = tid >> 10, kk = tid & 1023;
    o[tid] = f2bf(W[kk * HSn + n] * scale);  // W is 512KB fp32: L2-served
}

// ---------------------------------------------------------------------------
// Kernel 2: QKV projection. out = x @ W. x is fp32 (converted to bf16 during
// LDS staging); Wt is bf16 [n][k] (gemm_bt pattern: A and B fragments are
// contiguous-k 16B LDS reads). Tile 128x128, BK=32, mfma 16x16x32_bf16.
// ws==0 -> q (scale pre-folded in Wt), ws==1 -> k, ws==2 -> V stored
// transposed vt[b][d][t] directly from the epilogue.
// ---------------------------------------------------------------------------
extern "C" __global__ __launch_bounds__(256, 2) void head_proj(
    const float* __restrict__ x, const u16* __restrict__ wt, u16* __restrict__ qo,
    u16* __restrict__ ko, u16* __restrict__ vto) {
    __shared__ __align__(16) u16 aL[128 * 40];  // 128 rows x (32 + 8 pad)
    __shared__ __align__(16) u16 bL[128 * 40];
    const int tid = threadIdx.x;
    const int w = tid >> 6, l = tid & 63, quad = l >> 4, ln = l & 15;
    const int bm0 = blockIdx.x * 128;
    const int ws = blockIdx.y;
    const u16* wtw = wt + (size_t)ws * Cn * HSn;

    const f32x4 zero4 = {0.f, 0.f, 0.f, 0.f};
    f32x4 acc[4][4];
#pragma unroll
    for (int i = 0; i < 4; i++)
#pragma unroll
        for (int j = 0; j < 4; j++) acc[i][j] = zero4;

    const int m0w = (w & 1) * 64, n0w = (w >> 1) * 64;

    for (int kt = 0; kt < Cn / 32; kt++) {
        __syncthreads();
        // stage x tile: 128 rows x 32 k, fp32 -> bf16
#pragma unroll
        for (int p = 0; p < 4; p++) {
            int idx = p * 256 + tid;  // [0,1024)
            int row = idx >> 3, ch = idx & 7;
            f32x4 va = *(const f32x4*)(x + ((size_t)(bm0 + row)) * Cn + kt * 32 + ch * 4);
            u16x4 vb;
#pragma unroll
            for (int j = 0; j < 4; j++) vb[j] = f2bf(va[j]);
            *(u16x4*)(aL + row * 40 + ch * 4) = vb;
        }
        // stage Wt tile (bf16): 128 rows x 32 k
#pragma unroll
        for (int p = 0; p < 2; p++) {
            int idx = p * 256 + tid;  // [0,512)
            int row = idx >> 2, ch = idx & 3;
            u16x8 vb = *(const u16x8*)(wtw + (size_t)row * Cn + kt * 32 + ch * 8);
            *(u16x8*)(bL + row * 40 + ch * 8) = vb;
        }
        __syncthreads();
        bf16x8 af[4], bf[4];
#pragma unroll
        for (int mi = 0; mi < 4; mi++) {
            int R = m0w + mi * 16 + ln;
            af[mi] = *(const bf16x8*)(aL + R * 40 + quad * 8);
        }
#pragma unroll
        for (int ni = 0; ni < 4; ni++) {
            int R = n0w + ni * 16 + ln;
            bf[ni] = *(const bf16x8*)(bL + R * 40 + quad * 8);
        }
#pragma unroll
        for (int mi = 0; mi < 4; mi++)
#pragma unroll
            for (int ni = 0; ni < 4; ni++)
                acc[mi][ni] = __builtin_amdgcn_mfma_f32_16x16x32_bf16(
                    af[mi], bf[ni], acc[mi][ni], 0, 0, 0);
    }
    // epilogue: C-layout row = quad*4+reg, col = lane&15
    if (ws == 2) {
        // V: store transposed vt[b][d=col][t]
#pragma unroll
        for (int mi = 0; mi < 4; mi++)
#pragma unroll
            for (int ni = 0; ni < 4; ni++)
#pragma unroll
                for (int r = 0; r < 4; r++) {
                    int grow = bm0 + m0w + mi * 16 + quad * 4 + r;  // (b,t) flat
                    int bb = grow >> 12, t = grow & 4095;
                    int col = n0w + ni * 16 + ln;
                    vto[((size_t)bb * HSn + col) * Tn + t] = f2bf(acc[mi][ni][r]);
                }
    } else {
        u16* out = (ws == 0) ? qo : ko;
#pragma unroll
        for (int mi = 0; mi < 4; mi++)
#pragma unroll
            for (int ni = 0; ni < 4; ni++)
#pragma unroll
                for (int r = 0; r < 4; r++) {
                    int grow = bm0 + m0w + mi * 16 + quad * 4 + r;
                    int col = n0w + ni * 16 + ln;
                    out[(size_t)grow * HSn + col] = f2bf(acc[mi][ni][r]);
                }
    }
}

// ---------------------------------------------------------------------------
// Kernel 3: flash attention with pyramid band mask.
// Block = (b, 64-row q tile); wave w owns rows [q0+16w, q0+16w+16).
// Band: row r valid cols [2047 - r/2, 2047 + (r+1)/2]  (width r+1; verified
// against the numpy pyr construction incl. r=0 width-1 and the bot half).
// Tile loop covers the tile-union [L(qmax)/64, R(qmax)/64]. Rows before their
// first valid tile produce transient P=1 rows; alpha=exp2(-1e30-m)=0 washes
// them out exactly at the row's first valid tile (m starts at -1e30).
// Output is fp32.
// ---------------------------------------------------------------------------
extern "C" __global__ __launch_bounds__(256, 2) void head_flash(
    const u16* __restrict__ q, const u16* __restrict__ k, const u16* __restrict__ vt,
    float* __restrict__ out) {
    __shared__ __align__(16) u16 kL[64 * 136];     // [t][d], 128+8 pad
    __shared__ __align__(16) u16 vL[128 * 72];     // [d][t], 64+8 pad
    __shared__ __align__(16) u16 pL[4 * 16 * 72];  // per-wave 16 x (64+8)
    const int tid = threadIdx.x;
    const int w = tid >> 6, l = tid & 63, quad = l >> 4, ln = l & 15;
    const int b = blockIdx.y;
    const int qb = 63 - (int)blockIdx.x;  // biggest tiles launch first
    const int q0 = qb * 64;
    const int qrow = q0 + w * 16;

    // A-operand q fragments (A[m=lane&15][k=quad*8+j]); scale folded in Wq
    bf16x8 qf[4];
#pragma unroll
    for (int ks = 0; ks < 4; ks++)
        qf[ks] = *(const bf16x8*)(q + ((size_t)b * Tn + qrow + ln) * HSn + ks * 32 +
                                  quad * 8);

    const f32x4 zero4 = {0.f, 0.f, 0.f, 0.f};
    float m2[4], l2[4];
    f32x4 o[8];
#pragma unroll
    for (int r = 0; r < 4; r++) {
        m2[r] = -1e30f;
        l2[r] = 0.f;
    }
#pragma unroll
    for (int dt = 0; dt < 8; dt++) o[dt] = zero4;

    const int qmax = q0 + 63;
    const int tlo = (2047 - (qmax >> 1)) >> 6;
    const int thi = (2047 + ((qmax + 1) >> 1)) >> 6;

    for (int kt = tlo; kt <= thi; kt++) {
        const int t0 = kt * 64;
        __syncthreads();
#pragma unroll
        for (int p = 0; p < 4; p++) {  // K tile: 64 x 128
            int idx = p * 256 + tid;
            int row = idx >> 4, ch = idx & 15;
            u16x8 val = *(const u16x8*)(k + ((size_t)b * Tn + t0 + row) * HSn + ch * 8);
            *(u16x8*)(kL + row * 136 + ch * 8) = val;
        }
#pragma unroll
        for (int p = 0; p < 4; p++) {  // Vt tile: 128 x 64
            int idx = p * 256 + tid;
            int row = idx >> 3, ch = idx & 7;
            u16x8 val = *(const u16x8*)(vt + ((size_t)b * HSn + row) * Tn + t0 + ch * 8);
            *(u16x8*)(vL + row * 72 + ch * 8) = val;
        }
        __syncthreads();

        // S = q @ k^T  (16 q-rows x 64 cols per wave)
        f32x4 s[4];
#pragma unroll
        for (int nt = 0; nt < 4; nt++) s[nt] = zero4;
#pragma unroll
        for (int nt = 0; nt < 4; nt++) {
            int R = nt * 16 + ln;
#pragma unroll
            for (int ks = 0; ks < 4; ks++) {
                bf16x8 kf = *(const bf16x8*)(kL + R * 136 + (ks * 4 + quad) * 8);
                s[nt] = __builtin_amdgcn_mfma_f32_16x16x32_bf16(qf[ks], kf, s[nt], 0, 0, 0);
            }
        }
        // band mask (C-layout: row = quad*4+r, col = ln per 16-col tile)
#pragma unroll
        for (int nt = 0; nt < 4; nt++)
#pragma unroll
            for (int r = 0; r < 4; r++) {
                int qa = qrow + quad * 4 + r;
                int c = t0 + nt * 16 + ln;
                bool valid = (c >= 2047 - (qa >> 1)) && (c <= 2047 + ((qa + 1) >> 1));
                s[nt][r] = valid ? s[nt][r] : -1e30f;
            }
        // online softmax (rows live per (quad, reg); reduce across 16 lanes)
        float mc[4];
#pragma unroll
        for (int r = 0; r < 4; r++) {
            float m = fmaxf(fmaxf(s[0][r], s[1][r]), fmaxf(s[2][r], s[3][r]));
#pragma unroll
            for (int off = 1; off < 16; off <<= 1) m = fmaxf(m, __shfl_xor(m, off, 64));
            mc[r] = m;
        }
        float alpha[4], mn[4], ls[4];
#pragma unroll
        for (int r = 0; r < 4; r++) {
            mn[r] = fmaxf(m2[r], mc[r]);
            alpha[r] = exp2f(m2[r] - mn[r]);
            m2[r] = mn[r];
            ls[r] = 0.f;
        }
#pragma unroll
        for (int nt = 0; nt < 4; nt++)
#pragma unroll
            for (int r = 0; r < 4; r++) {
                float pv = exp2f(s[nt][r] - mn[r]);
                u16 pb = f2bf(pv);
                ls[r] += bf2f(pb);  // l matches the bf16-rounded P used in PV
                pL[w * 1152 + (quad * 4 + r) * 72 + nt * 16 + ln] = pb;
            }
#pragma unroll
        for (int r = 0; r < 4; r++) {
            float t = ls[r];
#pragma unroll
            for (int off = 1; off < 16; off <<= 1) t += __shfl_xor(t, off, 64);
            l2[r] = l2[r] * alpha[r] + t;
        }
#pragma unroll
        for (int dt = 0; dt < 8; dt++) {
            f32x4 oo = o[dt];
#pragma unroll
            for (int r = 0; r < 4; r++) oo[r] *= alpha[r];
            o[dt] = oo;
        }
        // P LDS write -> read: full barrier for safety this round
        __syncthreads();
        // O += P @ V   (A = P from pL, B = Vt rows: contiguous t)
#pragma unroll
        for (int jt = 0; jt < 2; jt++) {
            bf16x8 pf = *(const bf16x8*)(pL + w * 1152 + ln * 72 + jt * 32 + quad * 8);
#pragma unroll
            for (int dt = 0; dt < 8; dt++) {
                int R = dt * 16 + ln;
                bf16x8 vf = *(const bf16x8*)(vL + R * 72 + (jt * 4 + quad) * 8);
                o[dt] = __builtin_amdgcn_mfma_f32_16x16x32_bf16(pf, vf, o[dt], 0, 0, 0);
            }
        }
    }
    float rl[4];
#pragma unroll
    for (int r = 0; r < 4; r++) rl[r] = 1.0f / l2[r];
#pragma unroll
    for (int dt = 0; dt < 8; dt++)
#pragma unroll
        for (int r = 0; r < 4; r++) {
            int row = qrow + quad * 4 + r;
            out[((size_t)b * Tn + row) * HSn + dt * 16 + ln] = o[dt][r] * rl[r];
        }
}

// ---------------------------------------------------------------------------
extern "C" void kernel_launch(void* const* d_in, const int* in_sizes, int n_in,
                              void* d_out, int out_size, void* d_ws, size_t ws_size,
                              hipStream_t stream) {
    const float* x = (const float*)d_in[0];
    const float* Wq = (const float*)d_in[1];
    const float* Wk = (const float*)d_in[2];
    const float* Wv = (const float*)d_in[3];
    float* outp = (float*)d_out;
    char* ws = (char*)d_ws;
    // ws layout (bytes): wt bf16 @0 (768KB), q bf16 @1MB (8MB), k bf16 @9MB
    // (8MB), vt bf16 @17MB (8MB). Total 25MB.
    u16* wt = (u16*)(ws);
    u16* qb = (u16*)(ws + (1u << 20));
    u16* kb = (u16*)(ws + (9u << 20));
    u16* vtb = (u16*)(ws + (17u << 20));

    head_wtrans<<<dim3(512, 3), 256, 0, stream>>>(Wq, Wk, Wv, wt);
    head_proj<<<dim3(256, 3), 256, 0, stream>>>(x, wt, qb, kb, vtb);
    head_flash<<<dim3(64, 8), 256, 0, stream>>>(qb, kb, vtb, outp);
}

// Round 4
// 366.823 us; speedup vs baseline: 1.3667x; 1.3667x over previous
//
#include <hip/hip_runtime.h>

typedef unsigned short u16;
typedef __attribute__((ext_vector_type(8))) short bf16x8;
typedef __attribute__((ext_vector_type(8))) unsigned short u16x8;
typedef __attribute__((ext_vector_type(4))) float f32x4;
typedef __attribute__((ext_vector_type(4))) unsigned short u16x4;

#define Bn 8
#define Tn 4096
#define Cn 1024
#define HSn 128

__device__ __forceinline__ float bf2f(u16 b) {
    unsigned u = ((unsigned)b) << 16;
    return __builtin_bit_cast(float, u);
}
__device__ __forceinline__ u16 f2bf(float f) {
    unsigned u = __builtin_bit_cast(unsigned, f);
    unsigned r = (u + 0x7fffu + ((u >> 16) & 1u)) >> 16;
    return (u16)r;
}

// ---------------------------------------------------------------------------
// Kernel 1: W fp32 [k][n] (1024x128) -> Wt bf16 [n][k] (128x1024), x3.
// Softmax scale * log2(e) folded into Wq.
// ---------------------------------------------------------------------------
extern "C" __global__ __launch_bounds__(256) void head_wtrans(
    const float* __restrict__ Wq, const float* __restrict__ Wk,
    const float* __restrict__ Wv, u16* __restrict__ wt) {
    const float* W = (blockIdx.y == 0) ? Wq : (blockIdx.y == 1) ? Wk : Wv;
    const float scale =
        (blockIdx.y == 0) ? (0.08838834764831845f * 1.4426950408889634f) : 1.0f;
    u16* o = wt + (size_t)blockIdx.y * Cn * HSn;
    int tid = blockIdx.x * 256 + threadIdx.x;  // [0, 131072)
    int n = tid >> 10, kk = tid & 1023;
    o[tid] = f2bf(W[kk * HSn + n] * scale);  // W is 512KB fp32: L2-served
}

// ---------------------------------------------------------------------------
// Kernel 2: QKV projection (unchanged this round — surfacing its counters).
// out = x @ W. x fp32 -> bf16 during LDS staging; Wt bf16 [n][k].
// Tile 128x128, BK=32, mfma 16x16x32_bf16.
// ws==0 -> q, ws==1 -> k, ws==2 -> V stored transposed vt[b][d][t].
// ---------------------------------------------------------------------------
extern "C" __global__ __launch_bounds__(256, 2) void head_proj(
    const float* __restrict__ x, const u16* __restrict__ wt, u16* __restrict__ qo,
    u16* __restrict__ ko, u16* __restrict__ vto) {
    __shared__ __align__(16) u16 aL[128 * 40];  // 128 rows x (32 + 8 pad)
    __shared__ __align__(16) u16 bL[128 * 40];
    const int tid = threadIdx.x;
    const int w = tid >> 6, l = tid & 63, quad = l >> 4, ln = l & 15;
    const int bm0 = blockIdx.x * 128;
    const int ws = blockIdx.y;
    const u16* wtw = wt + (size_t)ws * Cn * HSn;

    const f32x4 zero4 = {0.f, 0.f, 0.f, 0.f};
    f32x4 acc[4][4];
#pragma unroll
    for (int i = 0; i < 4; i++)
#pragma unroll
        for (int j = 0; j < 4; j++) acc[i][j] = zero4;

    const int m0w = (w & 1) * 64, n0w = (w >> 1) * 64;

    for (int kt = 0; kt < Cn / 32; kt++) {
        __syncthreads();
        // stage x tile: 128 rows x 32 k, fp32 -> bf16
#pragma unroll
        for (int p = 0; p < 4; p++) {
            int idx = p * 256 + tid;  // [0,1024)
            int row = idx >> 3, ch = idx & 7;
            f32x4 va = *(const f32x4*)(x + ((size_t)(bm0 + row)) * Cn + kt * 32 + ch * 4);
            u16x4 vb;
#pragma unroll
            for (int j = 0; j < 4; j++) vb[j] = f2bf(va[j]);
            *(u16x4*)(aL + row * 40 + ch * 4) = vb;
        }
        // stage Wt tile (bf16): 128 rows x 32 k
#pragma unroll
        for (int p = 0; p < 2; p++) {
            int idx = p * 256 + tid;  // [0,512)
            int row = idx >> 2, ch = idx & 3;
            u16x8 vb = *(const u16x8*)(wtw + (size_t)row * Cn + kt * 32 + ch * 8);
            *(u16x8*)(bL + row * 40 + ch * 8) = vb;
        }
        __syncthreads();
        bf16x8 af[4], bf[4];
#pragma unroll
        for (int mi = 0; mi < 4; mi++) {
            int R = m0w + mi * 16 + ln;
            af[mi] = *(const bf16x8*)(aL + R * 40 + quad * 8);
        }
#pragma unroll
        for (int ni = 0; ni < 4; ni++) {
            int R = n0w + ni * 16 + ln;
            bf[ni] = *(const bf16x8*)(bL + R * 40 + quad * 8);
        }
#pragma unroll
        for (int mi = 0; mi < 4; mi++)
#pragma unroll
            for (int ni = 0; ni < 4; ni++)
                acc[mi][ni] = __builtin_amdgcn_mfma_f32_16x16x32_bf16(
                    af[mi], bf[ni], acc[mi][ni], 0, 0, 0);
    }
    // epilogue: C-layout row = quad*4+reg, col = lane&15
    if (ws == 2) {
#pragma unroll
        for (int mi = 0; mi < 4; mi++)
#pragma unroll
            for (int ni = 0; ni < 4; ni++)
#pragma unroll
                for (int r = 0; r < 4; r++) {
                    int grow = bm0 + m0w + mi * 16 + quad * 4 + r;  // (b,t) flat
                    int bb = grow >> 12, t = grow & 4095;
                    int col = n0w + ni * 16 + ln;
                    vto[((size_t)bb * HSn + col) * Tn + t] = f2bf(acc[mi][ni][r]);
                }
    } else {
        u16* out = (ws == 0) ? qo : ko;
#pragma unroll
        for (int mi = 0; mi < 4; mi++)
#pragma unroll
            for (int ni = 0; ni < 4; ni++)
#pragma unroll
                for (int r = 0; r < 4; r++) {
                    int grow = bm0 + m0w + mi * 16 + quad * 4 + r;
                    int col = n0w + ni * 16 + ln;
                    out[(size_t)grow * HSn + col] = f2bf(acc[mi][ni][r]);
                }
    }
}

// ---------------------------------------------------------------------------
// Kernel 3: flash attention with pyramid band mask — pair-balanced + prefetch.
// Block bx handles q-tiles {63-bx, bx}: band widths sum to ~66 k-tiles for
// every pair -> 256 equal-cost blocks (1/CU), no tail.
// Per k-tile iteration: prefetched registers -> LDS, issue next tile's global
// loads, then QK -> online softmax -> PV. pL is per-wave private (DS ops are
// wave-in-order) so no barrier before PV; 2 barriers/iter total.
// Band: row r valid cols [2047 - r/2, 2047 + (r+1)/2].
// ---------------------------------------------------------------------------
extern "C" __global__ __launch_bounds__(256) void head_flash(
    const u16* __restrict__ q, const u16* __restrict__ k, const u16* __restrict__ vt,
    float* __restrict__ out) {
    __shared__ __align__(16) u16 kL[64 * 136];     // [t][d], 128+8 pad
    __shared__ __align__(16) u16 vL[128 * 72];     // [d][t], 64+8 pad
    __shared__ __align__(16) u16 pL[4 * 16 * 72];  // per-wave 16 x (64+8)
    const int tid = threadIdx.x;
    const int w = tid >> 6, l = tid & 63, quad = l >> 4, ln = l & 15;
    const int b = blockIdx.y;
    const int bx = blockIdx.x;  // 0..31

    // fixed per-thread staging coordinates
    const int rkBase = tid >> 4, ckK = tid & 15;  // K: row = p*16 + rkBase
    const int rvBase = tid >> 3, ckV = tid & 7;   // V: row = p*32 + rvBase

    for (int phase = 0; phase < 2; phase++) {
        const int qb = phase == 0 ? 63 - bx : bx;
        const int q0 = qb * 64;
        const int qrow = q0 + w * 16;

        // A-operand q fragments (A[m=lane&15][k=quad*8+j]); scale folded in Wq
        bf16x8 qf[4];
#pragma unroll
        for (int ks = 0; ks < 4; ks++)
            qf[ks] = *(const bf16x8*)(q + ((size_t)b * Tn + qrow + ln) * HSn + ks * 32 +
                                      quad * 8);

        const f32x4 zero4 = {0.f, 0.f, 0.f, 0.f};
        float m2[4], l2[4];
        f32x4 o[8];
#pragma unroll
        for (int r = 0; r < 4; r++) {
            m2[r] = -1e30f;
            l2[r] = 0.f;
        }
#pragma unroll
        for (int dt = 0; dt < 8; dt++) o[dt] = zero4;

        const int qmax = q0 + 63;
        const int tlo = (2047 - (qmax >> 1)) >> 6;
        const int thi = (2047 + ((qmax + 1) >> 1)) >> 6;

        // prefetch first tile into registers
        u16x8 pk[4], pv[4];
        {
            const int t0 = tlo * 64;
#pragma unroll
            for (int p = 0; p < 4; p++)
                pk[p] = *(const u16x8*)(k + ((size_t)b * Tn + t0 + p * 16 + rkBase) * HSn +
                                        ckK * 8);
#pragma unroll
            for (int p = 0; p < 4; p++)
                pv[p] = *(const u16x8*)(vt + ((size_t)b * HSn + p * 32 + rvBase) * Tn +
                                        t0 + ckV * 8);
        }

        for (int kt = tlo; kt <= thi; kt++) {
            const int t0 = kt * 64;
            __syncthreads();  // prior-iter LDS reads complete
#pragma unroll
            for (int p = 0; p < 4; p++)
                *(u16x8*)(kL + (p * 16 + rkBase) * 136 + ckK * 8) = pk[p];
#pragma unroll
            for (int p = 0; p < 4; p++)
                *(u16x8*)(vL + (p * 32 + rvBase) * 72 + ckV * 8) = pv[p];
            // issue next tile's loads; they retire during this iter's compute
            if (kt < thi) {
                const int t1 = t0 + 64;
#pragma unroll
                for (int p = 0; p < 4; p++)
                    pk[p] = *(const u16x8*)(k + ((size_t)b * Tn + t1 + p * 16 + rkBase) *
                                                    HSn + ckK * 8);
#pragma unroll
                for (int p = 0; p < 4; p++)
                    pv[p] = *(const u16x8*)(vt + ((size_t)b * HSn + p * 32 + rvBase) * Tn +
                                            t1 + ckV * 8);
            }
            __syncthreads();  // staging visible

            // S = q @ k^T  (16 q-rows x 64 cols per wave)
            f32x4 s[4];
#pragma unroll
            for (int nt = 0; nt < 4; nt++) s[nt] = zero4;
#pragma unroll
            for (int nt = 0; nt < 4; nt++) {
                int R = nt * 16 + ln;
#pragma unroll
                for (int ks = 0; ks < 4; ks++) {
                    bf16x8 kf = *(const bf16x8*)(kL + R * 136 + (ks * 4 + quad) * 8);
                    s[nt] =
                        __builtin_amdgcn_mfma_f32_16x16x32_bf16(qf[ks], kf, s[nt], 0, 0, 0);
                }
            }
            // band mask (C-layout: row = quad*4+r, col = ln per 16-col tile)
#pragma unroll
            for (int nt = 0; nt < 4; nt++)
#pragma unroll
                for (int r = 0; r < 4; r++) {
                    int qa = qrow + quad * 4 + r;
                    int c = t0 + nt * 16 + ln;
                    bool valid = (c >= 2047 - (qa >> 1)) && (c <= 2047 + ((qa + 1) >> 1));
                    s[nt][r] = valid ? s[nt][r] : -1e30f;
                }
            // online softmax (rows live per (quad, reg); reduce across 16 lanes)
            float mc[4];
#pragma unroll
            for (int r = 0; r < 4; r++) {
                float m = fmaxf(fmaxf(s[0][r], s[1][r]), fmaxf(s[2][r], s[3][r]));
#pragma unroll
                for (int off = 1; off < 16; off <<= 1)
                    m = fmaxf(m, __shfl_xor(m, off, 64));
                mc[r] = m;
            }
            float alpha[4], mn[4], ls[4];
#pragma unroll
            for (int r = 0; r < 4; r++) {
                mn[r] = fmaxf(m2[r], mc[r]);
                alpha[r] = exp2f(m2[r] - mn[r]);
                m2[r] = mn[r];
                ls[r] = 0.f;
            }
#pragma unroll
            for (int nt = 0; nt < 4; nt++)
#pragma unroll
                for (int r = 0; r < 4; r++) {
                    float pv2 = exp2f(s[nt][r] - mn[r]);
                    u16 pb = f2bf(pv2);
                    ls[r] += bf2f(pb);  // l matches the bf16-rounded P used in PV
                    pL[w * 1152 + (quad * 4 + r) * 72 + nt * 16 + ln] = pb;
                }
#pragma unroll
            for (int r = 0; r < 4; r++) {
                float t = ls[r];
#pragma unroll
                for (int off = 1; off < 16; off <<= 1) t += __shfl_xor(t, off, 64);
                l2[r] = l2[r] * alpha[r] + t;
            }
#pragma unroll
            for (int dt = 0; dt < 8; dt++) {
                f32x4 oo = o[dt];
#pragma unroll
                for (int r = 0; r < 4; r++) oo[r] *= alpha[r];
                o[dt] = oo;
            }
            // O += P @ V  (pL is this wave's private region; DS is in-order
            // within a wave -> no barrier needed)
#pragma unroll
            for (int jt = 0; jt < 2; jt++) {
                bf16x8 pf = *(const bf16x8*)(pL + w * 1152 + ln * 72 + jt * 32 + quad * 8);
#pragma unroll
                for (int dt = 0; dt < 8; dt++) {
                    int R = dt * 16 + ln;
                    bf16x8 vf = *(const bf16x8*)(vL + R * 72 + (jt * 4 + quad) * 8);
                    o[dt] = __builtin_amdgcn_mfma_f32_16x16x32_bf16(pf, vf, o[dt], 0, 0, 0);
                }
            }
        }
        float rl[4];
#pragma unroll
        for (int r = 0; r < 4; r++) rl[r] = 1.0f / l2[r];
#pragma unroll
        for (int dt = 0; dt < 8; dt++)
#pragma unroll
            for (int r = 0; r < 4; r++) {
                int row = qrow + quad * 4 + r;
                out[((size_t)b * Tn + row) * HSn + dt * 16 + ln] = o[dt][r] * rl[r];
            }
    }
}

// ---------------------------------------------------------------------------
extern "C" void kernel_launch(void* const* d_in, const int* in_sizes, int n_in,
                              void* d_out, int out_size, void* d_ws, size_t ws_size,
                              hipStream_t stream) {
    const float* x = (const float*)d_in[0];
    const float* Wq = (const float*)d_in[1];
    const float* Wk = (const float*)d_in[2];
    const float* Wv = (const float*)d_in[3];
    float* outp = (float*)d_out;
    char* ws = (char*)d_ws;
    // ws layout (bytes): wt bf16 @0 (768KB), q bf16 @1MB (8MB), k bf16 @9MB
    // (8MB), vt bf16 @17MB (8MB). Total 25MB.
    u16* wt = (u16*)(ws);
    u16* qb = (u16*)(ws + (1u << 20));
    u16* kb = (u16*)(ws + (9u << 20));
    u16* vtb = (u16*)(ws + (17u << 20));

    head_wtrans<<<dim3(512, 3), 256, 0, stream>>>(Wq, Wk, Wv, wt);
    head_proj<<<dim3(256, 3), 256, 0, stream>>>(x, wt, qb, kb, vtb);
    head_flash<<<dim3(32, 8), 256, 0, stream>>>(qb, kb, vtb, outp);
}

// Round 5
// 347.635 us; speedup vs baseline: 1.4422x; 1.0552x over previous
//
#include <hip/hip_runtime.h>

typedef unsigned short u16;
typedef __attribute__((ext_vector_type(8))) short bf16x8;
typedef __attribute__((ext_vector_type(8))) unsigned short u16x8;
typedef __attribute__((ext_vector_type(4))) float f32x4;
typedef __attribute__((ext_vector_type(4))) unsigned short u16x4;

#define Bn 8
#define Tn 4096
#define Cn 1024
#define HSn 128

__device__ __forceinline__ float bf2f(u16 b) {
    unsigned u = ((unsigned)b) << 16;
    return __builtin_bit_cast(float, u);
}
__device__ __forceinline__ u16 f2bf(float f) {
    unsigned u = __builtin_bit_cast(unsigned, f);
    unsigned r = (u + 0x7fffu + ((u >> 16) & 1u)) >> 16;
    return (u16)r;
}

// ---------------------------------------------------------------------------
// Kernel 1: W fp32 [k][n] (1024x128) -> Wt bf16 [n][k] (128x1024), x3.
// Softmax scale * log2(e) folded into Wq.
// ---------------------------------------------------------------------------
extern "C" __global__ __launch_bounds__(256) void head_wtrans(
    const float* __restrict__ Wq, const float* __restrict__ Wk,
    const float* __restrict__ Wv, u16* __restrict__ wt) {
    const float* W = (blockIdx.y == 0) ? Wq : (blockIdx.y == 1) ? Wk : Wv;
    const float scale =
        (blockIdx.y == 0) ? (0.08838834764831845f * 1.4426950408889634f) : 1.0f;
    u16* o = wt + (size_t)blockIdx.y * Cn * HSn;
    int tid = blockIdx.x * 256 + threadIdx.x;  // [0, 131072)
    int n = tid >> 10, kk = tid & 1023;
    o[tid] = f2bf(W[kk * HSn + n] * scale);
}

// ---------------------------------------------------------------------------
// Kernel 2: FUSED QKV projection — single pass over x (reads x once, 128 MB).
// acc[3][4][4] f32x4 (~192 VGPR) + prefetch regs -> launch_bounds(256,1).
// HBM-bound: floor ~21 us for the x stream.
// ---------------------------------------------------------------------------
extern "C" __global__ __launch_bounds__(256, 1) void head_proj(
    const float* __restrict__ x, const u16* __restrict__ wt, u16* __restrict__ qo,
    u16* __restrict__ ko, u16* __restrict__ vto) {
    __shared__ __align__(16) u16 aL[128 * 40];      // x tile 128 x (32+8)
    __shared__ __align__(16) u16 bL[3 * 128 * 40];  // 3 W tiles
    const int tid = threadIdx.x;
    const int w = tid >> 6, l = tid & 63, quad = l >> 4, ln = l & 15;
    const int bm0 = blockIdx.x * 128;

    const f32x4 zero4 = {0.f, 0.f, 0.f, 0.f};
    f32x4 acc[3][4][4];
#pragma unroll
    for (int s = 0; s < 3; s++)
#pragma unroll
        for (int i = 0; i < 4; i++)
#pragma unroll
            for (int j = 0; j < 4; j++) acc[s][i][j] = zero4;

    const int m0w = (w & 1) * 64, n0w = (w >> 1) * 64;

    // prefetch registers
    f32x4 xp[4];
    u16x8 wp[3][2];
    const int xrow[4] = {tid >> 3, (256 + tid) >> 3, (512 + tid) >> 3, (768 + tid) >> 3};
    const int xch = tid & 7;
    const int wrow[2] = {tid >> 2, (256 + tid) >> 2};
    const int wch = tid & 3;

#pragma unroll
    for (int p = 0; p < 4; p++)
        xp[p] = *(const f32x4*)(x + ((size_t)(bm0 + xrow[p])) * Cn + xch * 4);
#pragma unroll
    for (int s = 0; s < 3; s++)
#pragma unroll
        for (int p = 0; p < 2; p++)
            wp[s][p] = *(const u16x8*)(wt + (size_t)s * Cn * HSn + (size_t)wrow[p] * Cn +
                                       wch * 8);

    for (int kt = 0; kt < Cn / 32; kt++) {
        __syncthreads();
        // commit prefetched tile to LDS
#pragma unroll
        for (int p = 0; p < 4; p++) {
            u16x4 vb;
#pragma unroll
            for (int j = 0; j < 4; j++) vb[j] = f2bf(xp[p][j]);
            *(u16x4*)(aL + xrow[p] * 40 + xch * 4) = vb;
        }
#pragma unroll
        for (int s = 0; s < 3; s++)
#pragma unroll
            for (int p = 0; p < 2; p++)
                *(u16x8*)(bL + s * 5120 + wrow[p] * 40 + wch * 8) = wp[s][p];
        // issue next tile's global loads (retire during compute)
        if (kt + 1 < Cn / 32) {
            const int kn = (kt + 1) * 32;
#pragma unroll
            for (int p = 0; p < 4; p++)
                xp[p] = *(const f32x4*)(x + ((size_t)(bm0 + xrow[p])) * Cn + kn + xch * 4);
#pragma unroll
            for (int s = 0; s < 3; s++)
#pragma unroll
                for (int p = 0; p < 2; p++)
                    wp[s][p] = *(const u16x8*)(wt + (size_t)s * Cn * HSn +
                                               (size_t)wrow[p] * Cn + kn + wch * 8);
        }
        __syncthreads();
        bf16x8 af[4];
#pragma unroll
        for (int mi = 0; mi < 4; mi++)
            af[mi] = *(const bf16x8*)(aL + (m0w + mi * 16 + ln) * 40 + quad * 8);
#pragma unroll
        for (int s = 0; s < 3; s++) {
            bf16x8 bf[4];
#pragma unroll
            for (int ni = 0; ni < 4; ni++)
                bf[ni] =
                    *(const bf16x8*)(bL + s * 5120 + (n0w + ni * 16 + ln) * 40 + quad * 8);
#pragma unroll
            for (int mi = 0; mi < 4; mi++)
#pragma unroll
                for (int ni = 0; ni < 4; ni++)
                    acc[s][mi][ni] = __builtin_amdgcn_mfma_f32_16x16x32_bf16(
                        af[mi], bf[ni], acc[s][mi][ni], 0, 0, 0);
        }
    }
    // epilogue: C-layout row = quad*4+reg, col = lane&15
#pragma unroll
    for (int mi = 0; mi < 4; mi++)
#pragma unroll
        for (int ni = 0; ni < 4; ni++)
#pragma unroll
            for (int r = 0; r < 4; r++) {
                int grow = bm0 + m0w + mi * 16 + quad * 4 + r;
                int col = n0w + ni * 16 + ln;
                qo[(size_t)grow * HSn + col] = f2bf(acc[0][mi][ni][r]);
                ko[(size_t)grow * HSn + col] = f2bf(acc[1][mi][ni][r]);
                int bb = grow >> 12, t = grow & 4095;
                vto[((size_t)bb * HSn + col) * Tn + t] = f2bf(acc[2][mi][ni][r]);
            }
}

// ---------------------------------------------------------------------------
// Kernel 3: flash attention, S^T formulation.
// Grid 512: first 256 blocks qb=63-p (big), last 256 qb=p (small) -> round-
// robin dispatch co-locates ~one big + one small block per CU (2 blocks/CU,
// 2 waves/SIMD). S^T = K·Q^T: softmax rows live per-lane (q = lane&15):
// row reductions = 15 VALU + 2 shfl; P written as 4x ds_write_b64.
// Band: row r valid cols [2047 - r/2, 2047 + (r+1)/2].
// ---------------------------------------------------------------------------
extern "C" __global__ __launch_bounds__(256) void head_flash(
    const u16* __restrict__ q, const u16* __restrict__ k, const u16* __restrict__ vt,
    float* __restrict__ out) {
    __shared__ __align__(16) u16 kL[64 * 136];     // [t][d], 128+8 pad
    __shared__ __align__(16) u16 vL[128 * 72];     // [d][t], 64+8 pad
    __shared__ __align__(16) u16 pL[4 * 16 * 72];  // per-wave P[q][t], 64+8 pad
    const int tid = threadIdx.x;
    const int w = tid >> 6, l = tid & 63, quad = l >> 4, ln = l & 15;
    const int bx = blockIdx.x;  // 0..511
    const int half = bx >> 8, idx = bx & 255;
    const int p5 = idx & 31, b = idx >> 5;
    const int qb = half ? p5 : 63 - p5;
    const int q0 = qb * 64;
    const int qrow = q0 + w * 16;

    // staging coordinates
    const int rkBase = tid >> 4, ckK = tid & 15;  // K: row = p*16 + rkBase
    const int rvBase = tid >> 3, ckV = tid & 7;   // V: row = p*32 + rvBase

    // Q fragments — B-operand for S^T (B[n=q=lane&15][k=quad*8+j])
    bf16x8 qf[4];
#pragma unroll
    for (int ks = 0; ks < 4; ks++)
        qf[ks] = *(const bf16x8*)(q + ((size_t)b * Tn + qrow + ln) * HSn + ks * 32 +
                                  quad * 8);

    const f32x4 zero4 = {0.f, 0.f, 0.f, 0.f};
    // per-lane softmax state for q = qrow + ln
    float m2 = -1e30f, l2 = 0.f;
    const int qme = qrow + ln;
    const int clo = 2047 - (qme >> 1), chi = 2047 + ((qme + 1) >> 1);
    f32x4 o[8];
#pragma unroll
    for (int dt = 0; dt < 8; dt++) o[dt] = zero4;

    const int qmax = q0 + 63;
    const int tlo = (2047 - (qmax >> 1)) >> 6;
    const int thi = (2047 + ((qmax + 1) >> 1)) >> 6;

    // prefetch first tile
    u16x8 pk[4], pv[4];
    {
        const int t0 = tlo * 64;
#pragma unroll
        for (int p = 0; p < 4; p++)
            pk[p] = *(const u16x8*)(k + ((size_t)b * Tn + t0 + p * 16 + rkBase) * HSn +
                                    ckK * 8);
#pragma unroll
        for (int p = 0; p < 4; p++)
            pv[p] = *(const u16x8*)(vt + ((size_t)b * HSn + p * 32 + rvBase) * Tn + t0 +
                                    ckV * 8);
    }

    for (int kt = tlo; kt <= thi; kt++) {
        const int t0 = kt * 64;
        __syncthreads();
#pragma unroll
        for (int p = 0; p < 4; p++)
            *(u16x8*)(kL + (p * 16 + rkBase) * 136 + ckK * 8) = pk[p];
#pragma unroll
        for (int p = 0; p < 4; p++)
            *(u16x8*)(vL + (p * 32 + rvBase) * 72 + ckV * 8) = pv[p];
        if (kt < thi) {
            const int t1 = t0 + 64;
#pragma unroll
            for (int p = 0; p < 4; p++)
                pk[p] = *(const u16x8*)(k + ((size_t)b * Tn + t1 + p * 16 + rkBase) * HSn +
                                        ckK * 8);
#pragma unroll
            for (int p = 0; p < 4; p++)
                pv[p] = *(const u16x8*)(vt + ((size_t)b * HSn + p * 32 + rvBase) * Tn +
                                        t1 + ckV * 8);
        }
        __syncthreads();

        // S^T = K·Q^T: D[m=t][n=q]; A = K frags, B = Q frags.
        f32x4 s[4];
#pragma unroll
        for (int nt = 0; nt < 4; nt++) s[nt] = zero4;
#pragma unroll
        for (int nt = 0; nt < 4; nt++) {
            int R = nt * 16 + ln;  // t-row
#pragma unroll
            for (int ks = 0; ks < 4; ks++) {
                bf16x8 kf = *(const bf16x8*)(kL + R * 136 + (ks * 4 + quad) * 8);
                s[nt] = __builtin_amdgcn_mfma_f32_16x16x32_bf16(kf, qf[ks], s[nt], 0, 0, 0);
            }
        }
        // mask: col q = ln (per-lane bounds precomputed), row t = quad*4+r
#pragma unroll
        for (int nt = 0; nt < 4; nt++)
#pragma unroll
            for (int r = 0; r < 4; r++) {
                int t = t0 + nt * 16 + quad * 4 + r;
                bool valid = (t >= clo) && (t <= chi);
                s[nt][r] = valid ? s[nt][r] : -1e30f;
            }
        // row stats: all 16 regs of a lane share q = qrow+ln; cross-quad via 2 shfl
        float mc = s[0][0];
#pragma unroll
        for (int nt = 0; nt < 4; nt++)
#pragma unroll
            for (int r = 0; r < 4; r++) mc = fmaxf(mc, s[nt][r]);
        mc = fmaxf(mc, __shfl_xor(mc, 16, 64));
        mc = fmaxf(mc, __shfl_xor(mc, 32, 64));
        float mn = fmaxf(m2, mc);
        float alpha = exp2f(m2 - mn);
        m2 = mn;
        float ls = 0.f;
#pragma unroll
        for (int nt = 0; nt < 4; nt++) {
            u16x4 pb4;
#pragma unroll
            for (int r = 0; r < 4; r++) {
                float pvx = exp2f(s[nt][r] - mn);
                u16 pb = f2bf(pvx);
                ls += bf2f(pb);
                pb4[r] = pb;
            }
            // P[q=ln][t = nt*16 + quad*4 + r] — 8B packed write
            *(u16x4*)(pL + w * 1152 + ln * 72 + nt * 16 + quad * 4) = pb4;
        }
        ls += __shfl_xor(ls, 16, 64);
        ls += __shfl_xor(ls, 32, 64);
        l2 = l2 * alpha + ls;
        // redistribute alpha to O rows (row = quad*4+r holds q = qrow+quad*4+r)
        float aR[4];
#pragma unroll
        for (int r = 0; r < 4; r++) aR[r] = __shfl(alpha, quad * 4 + r, 64);
#pragma unroll
        for (int dt = 0; dt < 8; dt++) {
            f32x4 oo = o[dt];
#pragma unroll
            for (int r = 0; r < 4; r++) oo[r] *= aR[r];
            o[dt] = oo;
        }
        // O += P·V  (A = P[q][t] from pL; B = Vt[d][t]); pL is wave-private,
        // DS in-order within a wave -> no barrier.
#pragma unroll
        for (int jt = 0; jt < 2; jt++) {
            bf16x8 pf = *(const bf16x8*)(pL + w * 1152 + ln * 72 + jt * 32 + quad * 8);
#pragma unroll
            for (int dt = 0; dt < 8; dt++) {
                int R = dt * 16 + ln;
                bf16x8 vf = *(const bf16x8*)(vL + R * 72 + (jt * 4 + quad) * 8);
                o[dt] = __builtin_amdgcn_mfma_f32_16x16x32_bf16(pf, vf, o[dt], 0, 0, 0);
            }
        }
    }
    float inv = 1.0f / l2;
    float rl[4];
#pragma unroll
    for (int r = 0; r < 4; r++) rl[r] = __shfl(inv, quad * 4 + r, 64);
#pragma unroll
    for (int dt = 0; dt < 8; dt++)
#pragma unroll
        for (int r = 0; r < 4; r++) {
            int row = qrow + quad * 4 + r;
            out[((size_t)b * Tn + row) * HSn + dt * 16 + ln] = o[dt][r] * rl[r];
        }
}

// ---------------------------------------------------------------------------
extern "C" void kernel_launch(void* const* d_in, const int* in_sizes, int n_in,
                              void* d_out, int out_size, void* d_ws, size_t ws_size,
                              hipStream_t stream) {
    const float* x = (const float*)d_in[0];
    const float* Wq = (const float*)d_in[1];
    const float* Wk = (const float*)d_in[2];
    const float* Wv = (const float*)d_in[3];
    float* outp = (float*)d_out;
    char* ws = (char*)d_ws;
    // ws layout: wt bf16 @0 (768KB), q @1MB, k @9MB, vt @17MB (8MB each).
    u16* wt = (u16*)(ws);
    u16* qb = (u16*)(ws + (1u << 20));
    u16* kb = (u16*)(ws + (9u << 20));
    u16* vtb = (u16*)(ws + (17u << 20));

    head_wtrans<<<dim3(512, 3), 256, 0, stream>>>(Wq, Wk, Wv, wt);
    head_proj<<<dim3(256), 256, 0, stream>>>(x, wt, qb, kb, vtb);
    head_flash<<<dim3(512), 256, 0, stream>>>(qb, kb, vtb, outp);
}

// Round 6
// 327.524 us; speedup vs baseline: 1.5307x; 1.0614x over previous
//
#include <hip/hip_runtime.h>

typedef unsigned short u16;
typedef __attribute__((ext_vector_type(8))) short bf16x8;
typedef __attribute__((ext_vector_type(8))) unsigned short u16x8;
typedef __attribute__((ext_vector_type(4))) float f32x4;
typedef __attribute__((ext_vector_type(4))) unsigned short u16x4;

#define Bn 8
#define Tn 4096
#define Cn 1024
#define HSn 128

__device__ __forceinline__ float bf2f(u16 b) {
    unsigned u = ((unsigned)b) << 16;
    return __builtin_bit_cast(float, u);
}
__device__ __forceinline__ u16 f2bf(float f) {
    unsigned u = __builtin_bit_cast(unsigned, f);
    unsigned r = (u + 0x7fffu + ((u >> 16) & 1u)) >> 16;
    return (u16)r;
}

// ---------------------------------------------------------------------------
// Kernel 1: W fp32 [k][n] (1024x128) -> Wt bf16 [n][k] (128x1024), x3.
// Softmax scale * log2(e) folded into Wq.
// ---------------------------------------------------------------------------
extern "C" __global__ __launch_bounds__(256) void head_wtrans(
    const float* __restrict__ Wq, const float* __restrict__ Wk,
    const float* __restrict__ Wv, u16* __restrict__ wt) {
    const float* W = (blockIdx.y == 0) ? Wq : (blockIdx.y == 1) ? Wk : Wv;
    const float scale =
        (blockIdx.y == 0) ? (0.08838834764831845f * 1.4426950408889634f) : 1.0f;
    u16* o = wt + (size_t)blockIdx.y * Cn * HSn;
    int tid = blockIdx.x * 256 + threadIdx.x;
    int n = tid >> 10, kk = tid & 1023;
    o[tid] = f2bf(W[kk * HSn + n] * scale);
}

// ---------------------------------------------------------------------------
// Kernel 2: FUSED QKV projection (unchanged this round — counters pending).
// ---------------------------------------------------------------------------
extern "C" __global__ __launch_bounds__(256, 1) void head_proj(
    const float* __restrict__ x, const u16* __restrict__ wt, u16* __restrict__ qo,
    u16* __restrict__ ko, u16* __restrict__ vto) {
    __shared__ __align__(16) u16 aL[128 * 40];
    __shared__ __align__(16) u16 bL[3 * 128 * 40];
    const int tid = threadIdx.x;
    const int w = tid >> 6, l = tid & 63, quad = l >> 4, ln = l & 15;
    const int bm0 = blockIdx.x * 128;

    const f32x4 zero4 = {0.f, 0.f, 0.f, 0.f};
    f32x4 acc[3][4][4];
#pragma unroll
    for (int s = 0; s < 3; s++)
#pragma unroll
        for (int i = 0; i < 4; i++)
#pragma unroll
            for (int j = 0; j < 4; j++) acc[s][i][j] = zero4;

    const int m0w = (w & 1) * 64, n0w = (w >> 1) * 64;

    f32x4 xp[4];
    u16x8 wp[3][2];
    const int xrow[4] = {tid >> 3, (256 + tid) >> 3, (512 + tid) >> 3, (768 + tid) >> 3};
    const int xch = tid & 7;
    const int wrow[2] = {tid >> 2, (256 + tid) >> 2};
    const int wch = tid & 3;

#pragma unroll
    for (int p = 0; p < 4; p++)
        xp[p] = *(const f32x4*)(x + ((size_t)(bm0 + xrow[p])) * Cn + xch * 4);
#pragma unroll
    for (int s = 0; s < 3; s++)
#pragma unroll
        for (int p = 0; p < 2; p++)
            wp[s][p] = *(const u16x8*)(wt + (size_t)s * Cn * HSn + (size_t)wrow[p] * Cn +
                                       wch * 8);

    for (int kt = 0; kt < Cn / 32; kt++) {
        __syncthreads();
#pragma unroll
        for (int p = 0; p < 4; p++) {
            u16x4 vb;
#pragma unroll
            for (int j = 0; j < 4; j++) vb[j] = f2bf(xp[p][j]);
            *(u16x4*)(aL + xrow[p] * 40 + xch * 4) = vb;
        }
#pragma unroll
        for (int s = 0; s < 3; s++)
#pragma unroll
            for (int p = 0; p < 2; p++)
                *(u16x8*)(bL + s * 5120 + wrow[p] * 40 + wch * 8) = wp[s][p];
        if (kt + 1 < Cn / 32) {
            const int kn = (kt + 1) * 32;
#pragma unroll
            for (int p = 0; p < 4; p++)
                xp[p] = *(const f32x4*)(x + ((size_t)(bm0 + xrow[p])) * Cn + kn + xch * 4);
#pragma unroll
            for (int s = 0; s < 3; s++)
#pragma unroll
                for (int p = 0; p < 2; p++)
                    wp[s][p] = *(const u16x8*)(wt + (size_t)s * Cn * HSn +
                                               (size_t)wrow[p] * Cn + kn + wch * 8);
        }
        __syncthreads();
        bf16x8 af[4];
#pragma unroll
        for (int mi = 0; mi < 4; mi++)
            af[mi] = *(const bf16x8*)(aL + (m0w + mi * 16 + ln) * 40 + quad * 8);
#pragma unroll
        for (int s = 0; s < 3; s++) {
            bf16x8 bf[4];
#pragma unroll
            for (int ni = 0; ni < 4; ni++)
                bf[ni] =
                    *(const bf16x8*)(bL + s * 5120 + (n0w + ni * 16 + ln) * 40 + quad * 8);
#pragma unroll
            for (int mi = 0; mi < 4; mi++)
#pragma unroll
                for (int ni = 0; ni < 4; ni++)
                    acc[s][mi][ni] = __builtin_amdgcn_mfma_f32_16x16x32_bf16(
                        af[mi], bf[ni], acc[s][mi][ni], 0, 0, 0);
        }
    }
#pragma unroll
    for (int mi = 0; mi < 4; mi++)
#pragma unroll
        for (int ni = 0; ni < 4; ni++)
#pragma unroll
            for (int r = 0; r < 4; r++) {
                int grow = bm0 + m0w + mi * 16 + quad * 4 + r;
                int col = n0w + ni * 16 + ln;
                qo[(size_t)grow * HSn + col] = f2bf(acc[0][mi][ni][r]);
                ko[(size_t)grow * HSn + col] = f2bf(acc[1][mi][ni][r]);
                int bb = grow >> 12, t = grow & 4095;
                vto[((size_t)bb * HSn + col) * Tn + t] = f2bf(acc[2][mi][ni][r]);
            }
}

// ===========================================================================
// Flash common device body: processes k-tiles [kstart, kend] for (b, qb),
// leaves unnormalized (m2, l2, o[8]) in the caller's registers.
// S^T = K·Q^T formulation; per-lane softmax state for q = qrow + (lane&15).
// ===========================================================================

// ---------------------------------------------------------------------------
// Kernel 3a: split-K flash chunk. 1024 blocks, cid = blockIdx.x:
//   qq = cid>>4 -> qb = 63-qq (big bands first); b = (cid&15)>>1; half = cid&1.
// Band [tlo,thi], W = thi-tlo+1 (>=2); c0 = ceil(W/2); half 0 -> first c0
// tiles, half 1 -> rest. Writes unnormalized partials:
//   Opart[cid][64][128] bf16, ml[cid][64][2] fp32 (m, l).
// Fully-masked rows in a chunk produce m=-1e30, l=0, O=0 -> zero weight in
// the combine. 45KB LDS / ~92 VGPR -> 3 blocks/CU co-resident.
// ---------------------------------------------------------------------------
extern "C" __global__ __launch_bounds__(256) void head_flash_chunk(
    const u16* __restrict__ q, const u16* __restrict__ k, const u16* __restrict__ vt,
    u16* __restrict__ Opart, float* __restrict__ ml) {
    __shared__ __align__(16) u16 kL[64 * 136];
    __shared__ __align__(16) u16 vL[128 * 72];
    __shared__ __align__(16) u16 pL[4 * 16 * 72];
    const int tid = threadIdx.x;
    const int w = tid >> 6, l = tid & 63, quad = l >> 4, ln = l & 15;
    const int cid = blockIdx.x;
    const int qb = 63 - (cid >> 4);
    const int b = (cid & 15) >> 1;
    const int half = cid & 1;
    const int q0 = qb * 64;
    const int qrow = q0 + w * 16;

    const int rkBase = tid >> 4, ckK = tid & 15;
    const int rvBase = tid >> 3, ckV = tid & 7;

    bf16x8 qf[4];
#pragma unroll
    for (int ks = 0; ks < 4; ks++)
        qf[ks] = *(const bf16x8*)(q + ((size_t)b * Tn + qrow + ln) * HSn + ks * 32 +
                                  quad * 8);

    const f32x4 zero4 = {0.f, 0.f, 0.f, 0.f};
    float m2 = -1e30f, l2 = 0.f;
    const int qme = qrow + ln;
    const int clo = 2047 - (qme >> 1), chi = 2047 + ((qme + 1) >> 1);
    f32x4 o[8];
#pragma unroll
    for (int dt = 0; dt < 8; dt++) o[dt] = zero4;

    const int qmax = q0 + 63;
    const int tlo = (2047 - (qmax >> 1)) >> 6;
    const int thi = (2047 + ((qmax + 1) >> 1)) >> 6;
    const int W = thi - tlo + 1;
    const int c0 = (W + 1) >> 1;
    const int kstart = half ? tlo + c0 : tlo;
    const int kend = half ? thi : tlo + c0 - 1;

    u16x8 pk[4], pv[4];
    {
        const int t0 = kstart * 64;
#pragma unroll
        for (int p = 0; p < 4; p++)
            pk[p] = *(const u16x8*)(k + ((size_t)b * Tn + t0 + p * 16 + rkBase) * HSn +
                                    ckK * 8);
#pragma unroll
        for (int p = 0; p < 4; p++)
            pv[p] = *(const u16x8*)(vt + ((size_t)b * HSn + p * 32 + rvBase) * Tn + t0 +
                                    ckV * 8);
    }

    for (int kt = kstart; kt <= kend; kt++) {
        const int t0 = kt * 64;
        __syncthreads();
#pragma unroll
        for (int p = 0; p < 4; p++)
            *(u16x8*)(kL + (p * 16 + rkBase) * 136 + ckK * 8) = pk[p];
#pragma unroll
        for (int p = 0; p < 4; p++)
            *(u16x8*)(vL + (p * 32 + rvBase) * 72 + ckV * 8) = pv[p];
        if (kt < kend) {
            const int t1 = t0 + 64;
#pragma unroll
            for (int p = 0; p < 4; p++)
                pk[p] = *(const u16x8*)(k + ((size_t)b * Tn + t1 + p * 16 + rkBase) * HSn +
                                        ckK * 8);
#pragma unroll
            for (int p = 0; p < 4; p++)
                pv[p] = *(const u16x8*)(vt + ((size_t)b * HSn + p * 32 + rvBase) * Tn +
                                        t1 + ckV * 8);
        }
        __syncthreads();

        f32x4 s[4];
#pragma unroll
        for (int nt = 0; nt < 4; nt++) s[nt] = zero4;
#pragma unroll
        for (int nt = 0; nt < 4; nt++) {
            int R = nt * 16 + ln;
#pragma unroll
            for (int ks = 0; ks < 4; ks++) {
                bf16x8 kf = *(const bf16x8*)(kL + R * 136 + (ks * 4 + quad) * 8);
                s[nt] = __builtin_amdgcn_mfma_f32_16x16x32_bf16(kf, qf[ks], s[nt], 0, 0, 0);
            }
        }
#pragma unroll
        for (int nt = 0; nt < 4; nt++)
#pragma unroll
            for (int r = 0; r < 4; r++) {
                int t = t0 + nt * 16 + quad * 4 + r;
                bool valid = (t >= clo) && (t <= chi);
                s[nt][r] = valid ? s[nt][r] : -1e30f;
            }
        float mc = s[0][0];
#pragma unroll
        for (int nt = 0; nt < 4; nt++)
#pragma unroll
            for (int r = 0; r < 4; r++) mc = fmaxf(mc, s[nt][r]);
        mc = fmaxf(mc, __shfl_xor(mc, 16, 64));
        mc = fmaxf(mc, __shfl_xor(mc, 32, 64));
        float mn = fmaxf(m2, mc);
        float alpha = exp2f(m2 - mn);
        m2 = mn;
        float ls = 0.f;
#pragma unroll
        for (int nt = 0; nt < 4; nt++) {
            u16x4 pb4;
#pragma unroll
            for (int r = 0; r < 4; r++) {
                float pvx = exp2f(s[nt][r] - mn);
                u16 pb = f2bf(pvx);
                ls += bf2f(pb);
                pb4[r] = pb;
            }
            *(u16x4*)(pL + w * 1152 + ln * 72 + nt * 16 + quad * 4) = pb4;
        }
        ls += __shfl_xor(ls, 16, 64);
        ls += __shfl_xor(ls, 32, 64);
        l2 = l2 * alpha + ls;
        float aR[4];
#pragma unroll
        for (int r = 0; r < 4; r++) aR[r] = __shfl(alpha, quad * 4 + r, 64);
#pragma unroll
        for (int dt = 0; dt < 8; dt++) {
            f32x4 oo = o[dt];
#pragma unroll
            for (int r = 0; r < 4; r++) oo[r] *= aR[r];
            o[dt] = oo;
        }
#pragma unroll
        for (int jt = 0; jt < 2; jt++) {
            bf16x8 pf = *(const bf16x8*)(pL + w * 1152 + ln * 72 + jt * 32 + quad * 8);
#pragma unroll
            for (int dt = 0; dt < 8; dt++) {
                int R = dt * 16 + ln;
                bf16x8 vf = *(const bf16x8*)(vL + R * 72 + (jt * 4 + quad) * 8);
                o[dt] = __builtin_amdgcn_mfma_f32_16x16x32_bf16(pf, vf, o[dt], 0, 0, 0);
            }
        }
    }
    // partials: unnormalized O (bf16) + per-row (m, l)
#pragma unroll
    for (int dt = 0; dt < 8; dt++)
#pragma unroll
        for (int r = 0; r < 4; r++)
            Opart[((size_t)cid * 64 + w * 16 + quad * 4 + r) * HSn + dt * 16 + ln] =
                f2bf(o[dt][r]);
    if (l < 16) {
        ml[((size_t)cid * 64 + w * 16 + ln) * 2 + 0] = m2;
        ml[((size_t)cid * 64 + w * 16 + ln) * 2 + 1] = l2;
    }
}

// ---------------------------------------------------------------------------
// Kernel 3b: combine 2 chunks per (b,qb): out = sum(w_i O_i) / sum(w_i l_i),
// w_i = 2^(m_i - max m). 512 blocks x 256 threads; thread = (row 0..63, 32-col
// segment). HBM-bound (~80 MB total).
// ---------------------------------------------------------------------------
extern "C" __global__ __launch_bounds__(256) void head_combine(
    const u16* __restrict__ Opart, const float* __restrict__ ml,
    float* __restrict__ out) {
    const int bid = blockIdx.x;  // (qb,b)
    const int qb = bid >> 3, b = bid & 7;
    const int tid = threadIdx.x;
    const int row = tid >> 2, dseg = (tid & 3) * 32;
    const int cid0 = (63 - qb) * 16 + b * 2;
    const size_t r0 = (size_t)cid0 * 64 + row, r1 = r0 + 64;
    float m0 = ml[r0 * 2], l0 = ml[r0 * 2 + 1];
    float m1 = ml[r1 * 2], l1 = ml[r1 * 2 + 1];
    float ms = fmaxf(m0, m1);
    float w0 = exp2f(m0 - ms), w1 = exp2f(m1 - ms);
    float inv = 1.0f / (w0 * l0 + w1 * l1);
    float* op = out + ((size_t)b * Tn + qb * 64 + row) * HSn + dseg;
    const u16* p0 = Opart + r0 * HSn + dseg;
    const u16* p1 = Opart + r1 * HSn + dseg;
#pragma unroll
    for (int j = 0; j < 4; j++) {
        u16x8 a = *(const u16x8*)(p0 + j * 8);
        u16x8 c = *(const u16x8*)(p1 + j * 8);
        f32x4 o1, o2;
#pragma unroll
        for (int e = 0; e < 4; e++) o1[e] = (w0 * bf2f(a[e]) + w1 * bf2f(c[e])) * inv;
#pragma unroll
        for (int e = 0; e < 4; e++) o2[e] = (w0 * bf2f(a[4 + e]) + w1 * bf2f(c[4 + e])) * inv;
        *(f32x4*)(op + j * 8) = o1;
        *(f32x4*)(op + j * 8 + 4) = o2;
    }
}

// ---------------------------------------------------------------------------
// Kernel 3-mono (fallback when ws too small for partials): round-5 flash.
// ---------------------------------------------------------------------------
extern "C" __global__ __launch_bounds__(256) void head_flash(
    const u16* __restrict__ q, const u16* __restrict__ k, const u16* __restrict__ vt,
    float* __restrict__ out) {
    __shared__ __align__(16) u16 kL[64 * 136];
    __shared__ __align__(16) u16 vL[128 * 72];
    __shared__ __align__(16) u16 pL[4 * 16 * 72];
    const int tid = threadIdx.x;
    const int w = tid >> 6, l = tid & 63, quad = l >> 4, ln = l & 15;
    const int bx = blockIdx.x;
    const int half = bx >> 8, idx = bx & 255;
    const int p5 = idx & 31, b = idx >> 5;
    const int qb = half ? p5 : 63 - p5;
    const int q0 = qb * 64;
    const int qrow = q0 + w * 16;
    const int rkBase = tid >> 4, ckK = tid & 15;
    const int rvBase = tid >> 3, ckV = tid & 7;

    bf16x8 qf[4];
#pragma unroll
    for (int ks = 0; ks < 4; ks++)
        qf[ks] = *(const bf16x8*)(q + ((size_t)b * Tn + qrow + ln) * HSn + ks * 32 +
                                  quad * 8);
    const f32x4 zero4 = {0.f, 0.f, 0.f, 0.f};
    float m2 = -1e30f, l2 = 0.f;
    const int qme = qrow + ln;
    const int clo = 2047 - (qme >> 1), chi = 2047 + ((qme + 1) >> 1);
    f32x4 o[8];
#pragma unroll
    for (int dt = 0; dt < 8; dt++) o[dt] = zero4;
    const int qmax = q0 + 63;
    const int tlo = (2047 - (qmax >> 1)) >> 6;
    const int thi = (2047 + ((qmax + 1) >> 1)) >> 6;

    u16x8 pk[4], pv[4];
    {
        const int t0 = tlo * 64;
#pragma unroll
        for (int p = 0; p < 4; p++)
            pk[p] = *(const u16x8*)(k + ((size_t)b * Tn + t0 + p * 16 + rkBase) * HSn +
                                    ckK * 8);
#pragma unroll
        for (int p = 0; p < 4; p++)
            pv[p] = *(const u16x8*)(vt + ((size_t)b * HSn + p * 32 + rvBase) * Tn + t0 +
                                    ckV * 8);
    }
    for (int kt = tlo; kt <= thi; kt++) {
        const int t0 = kt * 64;
        __syncthreads();
#pragma unroll
        for (int p = 0; p < 4; p++)
            *(u16x8*)(kL + (p * 16 + rkBase) * 136 + ckK * 8) = pk[p];
#pragma unroll
        for (int p = 0; p < 4; p++)
            *(u16x8*)(vL + (p * 32 + rvBase) * 72 + ckV * 8) = pv[p];
        if (kt < thi) {
            const int t1 = t0 + 64;
#pragma unroll
            for (int p = 0; p < 4; p++)
                pk[p] = *(const u16x8*)(k + ((size_t)b * Tn + t1 + p * 16 + rkBase) * HSn +
                                        ckK * 8);
#pragma unroll
            for (int p = 0; p < 4; p++)
                pv[p] = *(const u16x8*)(vt + ((size_t)b * HSn + p * 32 + rvBase) * Tn +
                                        t1 + ckV * 8);
        }
        __syncthreads();
        f32x4 s[4];
#pragma unroll
        for (int nt = 0; nt < 4; nt++) s[nt] = zero4;
#pragma unroll
        for (int nt = 0; nt < 4; nt++) {
            int R = nt * 16 + ln;
#pragma unroll
            for (int ks = 0; ks < 4; ks++) {
                bf16x8 kf = *(const bf16x8*)(kL + R * 136 + (ks * 4 + quad) * 8);
                s[nt] = __builtin_amdgcn_mfma_f32_16x16x32_bf16(kf, qf[ks], s[nt], 0, 0, 0);
            }
        }
#pragma unroll
        for (int nt = 0; nt < 4; nt++)
#pragma unroll
            for (int r = 0; r < 4; r++) {
                int t = t0 + nt * 16 + quad * 4 + r;
                bool valid = (t >= clo) && (t <= chi);
                s[nt][r] = valid ? s[nt][r] : -1e30f;
            }
        float mc = s[0][0];
#pragma unroll
        for (int nt = 0; nt < 4; nt++)
#pragma unroll
            for (int r = 0; r < 4; r++) mc = fmaxf(mc, s[nt][r]);
        mc = fmaxf(mc, __shfl_xor(mc, 16, 64));
        mc = fmaxf(mc, __shfl_xor(mc, 32, 64));
        float mn = fmaxf(m2, mc);
        float alpha = exp2f(m2 - mn);
        m2 = mn;
        float ls = 0.f;
#pragma unroll
        for (int nt = 0; nt < 4; nt++) {
            u16x4 pb4;
#pragma unroll
            for (int r = 0; r < 4; r++) {
                float pvx = exp2f(s[nt][r] - mn);
                u16 pb = f2bf(pvx);
                ls += bf2f(pb);
                pb4[r] = pb;
            }
            *(u16x4*)(pL + w * 1152 + ln * 72 + nt * 16 + quad * 4) = pb4;
        }
        ls += __shfl_xor(ls, 16, 64);
        ls += __shfl_xor(ls, 32, 64);
        l2 = l2 * alpha + ls;
        float aR[4];
#pragma unroll
        for (int r = 0; r < 4; r++) aR[r] = __shfl(alpha, quad * 4 + r, 64);
#pragma unroll
        for (int dt = 0; dt < 8; dt++) {
            f32x4 oo = o[dt];
#pragma unroll
            for (int r = 0; r < 4; r++) oo[r] *= aR[r];
            o[dt] = oo;
        }
#pragma unroll
        for (int jt = 0; jt < 2; jt++) {
            bf16x8 pf = *(const bf16x8*)(pL + w * 1152 + ln * 72 + jt * 32 + quad * 8);
#pragma unroll
            for (int dt = 0; dt < 8; dt++) {
                int R = dt * 16 + ln;
                bf16x8 vf = *(const bf16x8*)(vL + R * 72 + (jt * 4 + quad) * 8);
                o[dt] = __builtin_amdgcn_mfma_f32_16x16x32_bf16(pf, vf, o[dt], 0, 0, 0);
            }
        }
    }
    float inv = 1.0f / l2;
    float rl[4];
#pragma unroll
    for (int r = 0; r < 4; r++) rl[r] = __shfl(inv, quad * 4 + r, 64);
#pragma unroll
    for (int dt = 0; dt < 8; dt++)
#pragma unroll
        for (int r = 0; r < 4; r++) {
            int row = qrow + quad * 4 + r;
            out[((size_t)b * Tn + row) * HSn + dt * 16 + ln] = o[dt][r] * rl[r];
        }
}

// ---------------------------------------------------------------------------
extern "C" void kernel_launch(void* const* d_in, const int* in_sizes, int n_in,
                              void* d_out, int out_size, void* d_ws, size_t ws_size,
                              hipStream_t stream) {
    const float* x = (const float*)d_in[0];
    const float* Wq = (const float*)d_in[1];
    const float* Wk = (const float*)d_in[2];
    const float* Wv = (const float*)d_in[3];
    float* outp = (float*)d_out;
    char* ws = (char*)d_ws;
    // ws: wt @0 (768KB), q @1MB, k @9MB, vt @17MB (8MB each),
    // Opart bf16 @25MB (16.78MB), ml fp32 @42MB (0.52MB) -> needs ~43MB.
    u16* wt = (u16*)(ws);
    u16* qb = (u16*)(ws + (1u << 20));
    u16* kb = (u16*)(ws + (9u << 20));
    u16* vtb = (u16*)(ws + (17u << 20));
    u16* Opart = (u16*)(ws + (25u << 20));
    float* ml = (float*)(ws + (42u << 20));

    head_wtrans<<<dim3(512, 3), 256, 0, stream>>>(Wq, Wk, Wv, wt);
    head_proj<<<dim3(256), 256, 0, stream>>>(x, wt, qb, kb, vtb);
    if (ws_size >= (44ull << 20)) {
        head_flash_chunk<<<dim3(1024), 256, 0, stream>>>(qb, kb, vtb, Opart, ml);
        head_combine<<<dim3(512), 256, 0, stream>>>(Opart, ml, outp);
    } else {
        head_flash<<<dim3(512), 256, 0, stream>>>(qb, kb, vtb, outp);
    }
}